// Round 9
// baseline (295.233 us; speedup 1.0000x reference)
//
#include <hip/hip_runtime.h>
#include <stdint.h>

#define NC 10     // clusters
#define EMB 64
#define DD 1024
#define NP 4096   // patches per bag
#define NB 8      // batch
#define BP 32     // patches per block
#define NBLK (NB * NP / BP)   // 1024 blocks
#define PPB (NP / BP)         // 128 partial blocks per bag
#define KCH 128               // k per chunk
#define NCHUNK (DD / KCH)     // 8
#define WFRAG_U32 65536       // 32 ksteps * 4 ct * 2 hl * 64 lanes * 4 u32 = 256KB

typedef __attribute__((ext_vector_type(4))) float f32x4;
typedef __attribute__((ext_vector_type(8))) short short8;

union FragU {
    uint32_t u[4];
    int4     i;
    short8   s;
};

// ---------- Prep: W1 fp32 -> bf16 hi/lo fragments in MFMA B-layout ----------
// uint4-index: kg*512 + ct*128 + hl*64 + lane
// e = ct*16 + (lane&15), k = kg*32 + (lane>>4)*8 + j   (16x16x32 B-frag layout)
__global__ __launch_bounds__(256) void prep_wfrag(
    const float* __restrict__ W1, uint32_t* __restrict__ wf)
{
    const int tid  = blockIdx.x * 256 + threadIdx.x;   // 0..16383
    const int lane = tid & 63;
    const int hl   = (tid >> 6) & 1;
    const int ct   = (tid >> 7) & 3;
    const int kg   = tid >> 9;                         // 0..31
    const int e    = ct * 16 + (lane & 15);
    const int k0   = kg * 32 + (lane >> 4) * 8;
    const float* src = W1 + (size_t)e * DD + k0;

    uint32_t out[4];
#pragma unroll
    for (int q = 0; q < 4; ++q) {
        float x0 = src[2 * q], x1 = src[2 * q + 1];
        uint32_t b0 = __float_as_uint(x0), b1 = __float_as_uint(x1);
        uint32_t h0 = (b0 + 0x7fffu + ((b0 >> 16) & 1u)) >> 16;   // RNE bf16
        uint32_t h1 = (b1 + 0x7fffu + ((b1 >> 16) & 1u)) >> 16;
        if (hl == 0) {
            out[q] = h0 | (h1 << 16);
        } else {
            float r0 = x0 - __uint_as_float(h0 << 16);
            float r1 = x1 - __uint_as_float(h1 << 16);
            uint32_t c0 = __float_as_uint(r0), c1 = __float_as_uint(r1);
            uint32_t l0 = (c0 + 0x7fffu + ((c0 >> 16) & 1u)) >> 16;
            uint32_t l1 = (c1 + 0x7fffu + ((c1 >> 16) & 1u)) >> 16;
            out[q] = l0 | (l1 << 16);
        }
    }
    *(uint4*)(wf + (size_t)tid * 4) = make_uint4(out[0], out[1], out[2], out[3]);
}

// ---------- K1: e = relu(data @ W1^T + b1) via 3-term bf16 MFMA + seg-sum ----
// 1024 blocks x 512 threads (8 waves) -> 4 blocks/CU, 32 waves/CU (100% occ).
// Wave w: patch-tile pt = w>>2 (16 patches), ct = w&3 (16 embs). acc = 4 VGPR.
// All loads direct from global; latency hidden by TLP (8 waves/SIMD).
__global__ __launch_bounds__(512, 8) void embed_mfma(
    const float* __restrict__ data, const int* __restrict__ labels,
    const uint32_t* __restrict__ wf, const float* __restrict__ b1,
    float* __restrict__ psum, float* __restrict__ pcnt, int use_atomic)
{
    __shared__ float csum[NC][EMB];
    __shared__ float ccnt[NC];
    __shared__ int   labs[BP];

    const int t    = threadIdx.x;
    const int lane = t & 63;
    const int w    = t >> 6;          // 0..7
    const int pt   = w >> 2;          // patch tile 0..1
    const int ct   = w & 3;           // ct 0..3
    const int bid  = blockIdx.x;
    const int bag  = bid >> 7;                 // 128 blocks per bag
    const int p0   = (bid & 127) * BP;

    for (int i = t; i < NC * EMB; i += 512) (&csum[0][0])[i] = 0.f;
    if (t < NC) ccnt[t] = 0.f;
    if (t < BP) labs[t] = labels[bag * NP + p0 + t];
    __syncthreads();

    // A: row = p0 + pt*16 + (lane&15); k-base = (lane>>4)*8
    const float* Ap = data + (size_t)(bag * NP + p0 + pt * 16 + (lane & 15)) * DD
                    + ((lane >> 4) << 3);
    // W: uint4-index kg*512 + ct*128 + hl*64 + lane
    const uint4* Wp = (const uint4*)wf + (size_t)(ct * 128 + lane);

    f32x4 acc = {};

#define PACK_HI(x0, x1) ((__float_as_uint(x1) & 0xffff0000u) | (__float_as_uint(x0) >> 16))

    for (int c = 0; c < NCHUNK; ++c) {
        // issue all chunk loads up-front (independent; one latency exposure)
        float4 a[8];
        uint4  bw[8];   // [ks] hi, then [ks] lo pairs interleaved: bw[2ks]=hi, bw[2ks+1]=lo
#pragma unroll
        for (int ks = 0; ks < 4; ++ks) {
            a[2 * ks]     = *(const float4*)(Ap + c * KCH + ks * 32);
            a[2 * ks + 1] = *(const float4*)(Ap + c * KCH + ks * 32 + 4);
        }
#pragma unroll
        for (int ks = 0; ks < 4; ++ks) {
            bw[2 * ks]     = Wp[(size_t)((c * 4 + ks) * 512)];        // hi
            bw[2 * ks + 1] = Wp[(size_t)((c * 4 + ks) * 512 + 64)];   // lo
        }
#pragma unroll
        for (int ks = 0; ks < 4; ++ks) {
            const float4 a0 = a[2 * ks], a1 = a[2 * ks + 1];
            FragU ahi, alo;
            ahi.u[0] = PACK_HI(a0.x, a0.y);
            ahi.u[1] = PACK_HI(a0.z, a0.w);
            ahi.u[2] = PACK_HI(a1.x, a1.y);
            ahi.u[3] = PACK_HI(a1.z, a1.w);
            float r0 = a0.x - __uint_as_float(__float_as_uint(a0.x) & 0xffff0000u);
            float r1 = a0.y - __uint_as_float(__float_as_uint(a0.y) & 0xffff0000u);
            float r2 = a0.z - __uint_as_float(__float_as_uint(a0.z) & 0xffff0000u);
            float r3 = a0.w - __uint_as_float(__float_as_uint(a0.w) & 0xffff0000u);
            float r4 = a1.x - __uint_as_float(__float_as_uint(a1.x) & 0xffff0000u);
            float r5 = a1.y - __uint_as_float(__float_as_uint(a1.y) & 0xffff0000u);
            float r6 = a1.z - __uint_as_float(__float_as_uint(a1.z) & 0xffff0000u);
            float r7 = a1.w - __uint_as_float(__float_as_uint(a1.w) & 0xffff0000u);
            alo.u[0] = PACK_HI(r0, r1);
            alo.u[1] = PACK_HI(r2, r3);
            alo.u[2] = PACK_HI(r4, r5);
            alo.u[3] = PACK_HI(r6, r7);
            FragU bhi, blo;
            bhi.i = *(const int4*)&bw[2 * ks];
            blo.i = *(const int4*)&bw[2 * ks + 1];
            acc = __builtin_amdgcn_mfma_f32_16x16x32_bf16(ahi.s, bhi.s, acc, 0, 0, 0);
            acc = __builtin_amdgcn_mfma_f32_16x16x32_bf16(ahi.s, blo.s, acc, 0, 0, 0);
            acc = __builtin_amdgcn_mfma_f32_16x16x32_bf16(alo.s, bhi.s, acc, 0, 0, 0);
        }
    }

    // ---- epilogue: bias + relu + per-cluster LDS accumulation ----
    // D-frag (verified r7/r8, absmax 0): emb = ct*16+(lane&15), patch = pt*16+(lane>>4)*4+r
    {
        const int emb = ct * 16 + (lane & 15);
        const float bb = b1[emb];
#pragma unroll
        for (int r = 0; r < 4; ++r) {
            const int patch = pt * 16 + (lane >> 4) * 4 + r;
            float v = fmaxf(acc[r] + bb, 0.f);
            atomicAdd(&csum[labs[patch]][emb], v);
        }
    }
    if (t < BP) atomicAdd(&ccnt[labs[t]], 1.0f);
    __syncthreads();

    if (use_atomic) {
        for (int i = t; i < NC * EMB; i += 512)
            atomicAdd(&psum[(size_t)bag * NC * EMB + i], (&csum[0][0])[i]);
        if (t < NC) atomicAdd(&pcnt[bag * NC + t], ccnt[t]);
    } else {
        for (int i = t; i < NC * EMB; i += 512)
            psum[(size_t)bid * NC * EMB + i] = (&csum[0][0])[i];
        if (t < NC) pcnt[bid * NC + t] = ccnt[t];
    }
}

// ---------- K2: reduce partials, means, attention, masked softmax, fc6 ------
__global__ __launch_bounds__(256) void head_kernel(
    const float* __restrict__ psum, const float* __restrict__ pcnt, int npb,
    const float* __restrict__ Wa1, const float* __restrict__ ba1,
    const float* __restrict__ Wa2, const float* __restrict__ ba2,
    const float* __restrict__ Wf1, const float* __restrict__ bf1,
    const float* __restrict__ Wf2, const float* __restrict__ bf2,
    float* __restrict__ out)
{
    __shared__ float h[NC][EMB];
    __shared__ float cnt_s[NC];
    __shared__ float mask[NC];
    __shared__ float att[NC][32];
    __shared__ float a_s[NC];
    __shared__ float A_s[NC];
    __shared__ float M_s[EMB];
    __shared__ float f_s[32];

    const int b = blockIdx.x;
    const int t = threadIdx.x;

    if (t < NC) {
        float s = 0.f;
        for (int pb = 0; pb < npb; ++pb) s += pcnt[(size_t)(b * npb + pb) * NC + t];
        cnt_s[t] = s;
        mask[t]  = s > 0.f ? 1.f : 0.f;
    }
    __syncthreads();
    for (int i = t; i < NC * EMB; i += 256) {
        float s = 0.f;
#pragma unroll 8
        for (int pb = 0; pb < npb; ++pb) s += psum[(size_t)(b * npb + pb) * NC * EMB + i];
        (&h[0][0])[i] = s / fmaxf(cnt_s[i >> 6], 1.f);
    }
    __syncthreads();

    for (int task = t; task < NC * 32; task += 256) {
        int c = task >> 5, hh = task & 31;
        float s = ba1[hh];
        for (int e = 0; e < EMB; ++e) s = fmaf(Wa1[hh * EMB + e], h[c][e], s);
        att[c][hh] = tanhf(s);
    }
    __syncthreads();

    if (t < NC) {
        float s = ba2[0];
        for (int hh = 0; hh < 32; ++hh) s = fmaf(Wa2[hh], att[t][hh], s);
        a_s[t] = s;
    }
    __syncthreads();

    if (t == 0) {
        // faithful to reference numeric trick
        float xmax = -1e30f;
        for (int c = 0; c < NC; ++c) {
            float xm = a_s[c] * mask[c] + (1.0f - 1.0f / (mask[c] + 1e-5f));
            xmax = fmaxf(xmax, xm);
        }
        float ex[NC], ssum = 0.f;
        for (int c = 0; c < NC; ++c) {
            ex[c] = expf(a_s[c] - xmax) * mask[c];
            ssum += ex[c];
        }
        for (int c = 0; c < NC; ++c) A_s[c] = ex[c] / ssum;
    }
    __syncthreads();

    if (t < EMB) {
        float s = 0.f;
        for (int c = 0; c < NC; ++c) s = fmaf(A_s[c], h[c][t], s);
        M_s[t] = s;
    }
    __syncthreads();

    if (t < 32) {
        float s = bf1[t];
        for (int e = 0; e < EMB; ++e) s = fmaf(Wf1[t * EMB + e], M_s[e], s);
        f_s[t] = fmaxf(s, 0.f);
    }
    __syncthreads();

    if (t == 0) {
        float s = bf2[0];
        for (int hh = 0; hh < 32; ++hh) s = fmaf(Wf2[hh], f_s[hh], s);
        out[b] = s;
    }
}

extern "C" void kernel_launch(void* const* d_in, const int* in_sizes, int n_in,
                              void* d_out, int out_size, void* d_ws, size_t ws_size,
                              hipStream_t stream)
{
    const float* data   = (const float*)d_in[0];
    const int*   labels = (const int*)  d_in[1];
    const float* W1     = (const float*)d_in[2];
    const float* b1     = (const float*)d_in[3];
    const float* Wa1    = (const float*)d_in[4];
    const float* ba1    = (const float*)d_in[5];
    const float* Wa2    = (const float*)d_in[6];
    const float* ba2    = (const float*)d_in[7];
    const float* Wf1    = (const float*)d_in[8];
    const float* bf1    = (const float*)d_in[9];
    const float* Wf2    = (const float*)d_in[10];
    const float* bf2    = (const float*)d_in[11];

    uint32_t* wfrag = (uint32_t*)d_ws;                       // 256KB
    float* psum = (float*)(wfrag + WFRAG_U32);

    prep_wfrag<<<64, 256, 0, stream>>>(W1, wfrag);

    const size_t need_na = (size_t)WFRAG_U32 * 4 +
                           ((size_t)NBLK * NC * EMB + (size_t)NBLK * NC) * sizeof(float);
    if (ws_size >= need_na) {
        float* pcnt = psum + (size_t)NBLK * NC * EMB;
        embed_mfma<<<NBLK, 512, 0, stream>>>(data, labels, wfrag, b1, psum, pcnt, 0);
        head_kernel<<<NB, 256, 0, stream>>>(psum, pcnt, PPB, Wa1, ba1, Wa2, ba2,
                                            Wf1, bf1, Wf2, bf2, (float*)d_out);
    } else {
        float* pcnt = psum + (size_t)NB * NC * EMB;
        hipMemsetAsync((void*)psum, 0,
                       (size_t)(NB * NC * EMB + NB * NC) * sizeof(float), stream);
        embed_mfma<<<NBLK, 512, 0, stream>>>(data, labels, wfrag, b1, psum, pcnt, 1);
        head_kernel<<<NB, 256, 0, stream>>>(psum, pcnt, 1, Wa1, ba1, Wa2, ba2,
                                            Wf1, bf1, Wf2, bf2, (float*)d_out);
    }
}

// Round 10
// 274.668 us; speedup vs baseline: 1.0749x; 1.0749x over previous
//
#include <hip/hip_runtime.h>
#include <stdint.h>

#define NC 10     // clusters
#define EMB 64
#define DD 1024
#define NP 4096   // patches per bag
#define NB 8      // batch
#define BP 32     // patches per block
#define NBLK (NB * NP / BP)   // 1024 blocks
#define PPB (NP / BP)         // 128 partial blocks per bag
#define NCHUNK 32             // BK = 32 k per chunk
#define WFRAG_U32 65536       // 32 kg * 512 uint4 * 16B = 256KB

typedef __attribute__((ext_vector_type(4))) float f32x4;
typedef __attribute__((ext_vector_type(8))) short short8;

union FragU { uint32_t u[4]; int4 i; short8 s; };

__device__ __forceinline__ void gld_lds16(const void* g, void* l) {
    __builtin_amdgcn_global_load_lds(
        (const __attribute__((address_space(1))) void*)g,
        (__attribute__((address_space(3))) void*)l, 16, 0, 0);
}

// ---------- Prep: W1 fp32 -> bf16 hi/lo fragments in MFMA B-layout ----------
// uint4-index: kg*512 + ct*128 + hl*64 + lane
// e = ct*16 + (lane&15), k = kg*32 + (lane>>4)*8 + j   (verified r7/r8: absmax 0)
__global__ __launch_bounds__(256) void prep_wfrag(
    const float* __restrict__ W1, uint32_t* __restrict__ wf)
{
    const int tid  = blockIdx.x * 256 + threadIdx.x;   // 0..16383
    const int lane = tid & 63;
    const int hl   = (tid >> 6) & 1;
    const int ct   = (tid >> 7) & 3;
    const int kg   = tid >> 9;                         // 0..31
    const int e    = ct * 16 + (lane & 15);
    const int k0   = kg * 32 + (lane >> 4) * 8;
    const float* src = W1 + (size_t)e * DD + k0;

    uint32_t out[4];
#pragma unroll
    for (int q = 0; q < 4; ++q) {
        float x0 = src[2 * q], x1 = src[2 * q + 1];
        uint32_t b0 = __float_as_uint(x0), b1 = __float_as_uint(x1);
        uint32_t h0 = (b0 + 0x7fffu + ((b0 >> 16) & 1u)) >> 16;   // RNE bf16
        uint32_t h1 = (b1 + 0x7fffu + ((b1 >> 16) & 1u)) >> 16;
        if (hl == 0) {
            out[q] = h0 | (h1 << 16);
        } else {
            float r0 = x0 - __uint_as_float(h0 << 16);
            float r1 = x1 - __uint_as_float(h1 << 16);
            uint32_t c0 = __float_as_uint(r0), c1 = __float_as_uint(r1);
            uint32_t l0 = (c0 + 0x7fffu + ((c0 >> 16) & 1u)) >> 16;
            uint32_t l1 = (c1 + 0x7fffu + ((c1 >> 16) & 1u)) >> 16;
            out[q] = l0 | (l1 << 16);
        }
    }
    *(uint4*)(wf + (size_t)tid * 4) = make_uint4(out[0], out[1], out[2], out[3]);
}

// ---------- K1: e = relu(data @ W1^T + b1), m97-style global_load_lds staging
// 1024 blocks x 256 threads (4 waves) -> 4 blocks/CU. Wave w = ct (16 embs).
// Per chunk (BK=32): A-tile [32 rows][32 k] fp32 (XOR-swizzled) + W frags 8KB,
// both staged via global_load_lds, double-buffered, 1 barrier per chunk.
__global__ __launch_bounds__(256, 4) void embed_mfma(
    const float* __restrict__ data, const int* __restrict__ labels,
    const uint32_t* __restrict__ wf, const float* __restrict__ b1,
    float* __restrict__ psum, float* __restrict__ pcnt, int use_atomic)
{
    __shared__ char  AsB[2][4096];    // A chunk buffers (swizzled rows of 128B)
    __shared__ uint4 Wl[2][512];      // W frag chunk buffers (8KB each)
    __shared__ float csum[NC][EMB];
    __shared__ float ccnt[NC];
    __shared__ int   labs[BP];

    const int t    = threadIdx.x;
    const int lane = t & 63;
    const int w    = t >> 6;          // wave id = ct
    const int bid  = blockIdx.x;
    const int bag  = bid >> 7;        // 128 blocks per bag
    const int p0   = (bid & 127) << 5;

    for (int i = t; i < NC * EMB; i += 256) (&csum[0][0])[i] = 0.f;
    if (t < NC) ccnt[t] = 0.f;
    if (t < BP) labs[t] = labels[bag * NP + p0 + t];

    const char* Abase = (const char*)data + (size_t)(bag * NP + p0) * 4096;
    const uint4* wf4  = (const uint4*)wf;

    // A staging: thread covers LDS bytes [w*1024 + lane*16); row = w*8+(lane>>3)
    // source col pre-swizzled: acol = ((lane&7)*16) ^ ((row&7)<<4), row&7 = lane>>3
    const int      arow = (w << 3) + (lane >> 3);
    const unsigned acol = (unsigned)(((lane & 7) << 4) ^ ((lane >> 3) << 4));
    const char* Asrc = Abase + (size_t)arow * 4096 + acol;      // + c*128
    char* Adst[2] = { (char*)&AsB[0][0] + (w << 10), (char*)&AsB[1][0] + (w << 10) };
    // W staging: load j: LDS uint4 idx j*256 + w*64 + lane <- global c*512 + same
    const uint4* Wsrc = wf4 + (w << 6) + lane;                  // + c*512 + j*256
    char* Wdst[2] = { (char*)&Wl[0][0] + (w << 10), (char*)&Wl[1][0] + (w << 10) };

    // ---- prologue: stage chunk 0 into buf 0 ----
    gld_lds16(Asrc, Adst[0]);
    gld_lds16(Wsrc, Wdst[0]);
    gld_lds16(Wsrc + 256, Wdst[0] + 4096);
    __syncthreads();

    f32x4 acc[2] = {};
    const unsigned sw   = (unsigned)((lane & 7) << 4);
    const unsigned cb0  = (unsigned)((lane >> 4) << 5);
    const unsigned alo_ = cb0 ^ sw;                       // lower 16B within row
    const unsigned row0 = ((unsigned)(lane & 15)) << 7;   // row*128 (pt=0)

#define PACK_HI(x0, x1) ((__float_as_uint(x1) & 0xffff0000u) | (__float_as_uint(x0) >> 16))

    for (int c = 0; c < NCHUNK; ++c) {
        const int buf = c & 1;
        const char* asb = &AsB[buf][0];
        if (c + 1 < NCHUNK) {   // prefetch next chunk into other buffer
            gld_lds16(Asrc + (c + 1) * 128, Adst[buf ^ 1]);
            const uint4* ws = Wsrc + (size_t)(c + 1) * 512;
            gld_lds16(ws, Wdst[buf ^ 1]);
            gld_lds16(ws + 256, Wdst[buf ^ 1] + 4096);
        }
        FragU bhi, blo;
        bhi.i = *(const int4*)&Wl[buf][(w << 7) + lane];
        blo.i = *(const int4*)&Wl[buf][(w << 7) + 64 + lane];
#pragma unroll
        for (int pt = 0; pt < 2; ++pt) {
            const float4 a0 = *(const float4*)(asb + (pt << 11) + row0 + alo_);
            const float4 a1 = *(const float4*)(asb + (pt << 11) + row0 + (alo_ ^ 16u));
            FragU ahi, alo;
            ahi.u[0] = PACK_HI(a0.x, a0.y);
            ahi.u[1] = PACK_HI(a0.z, a0.w);
            ahi.u[2] = PACK_HI(a1.x, a1.y);
            ahi.u[3] = PACK_HI(a1.z, a1.w);
            float r0 = a0.x - __uint_as_float(__float_as_uint(a0.x) & 0xffff0000u);
            float r1 = a0.y - __uint_as_float(__float_as_uint(a0.y) & 0xffff0000u);
            float r2 = a0.z - __uint_as_float(__float_as_uint(a0.z) & 0xffff0000u);
            float r3 = a0.w - __uint_as_float(__float_as_uint(a0.w) & 0xffff0000u);
            float r4 = a1.x - __uint_as_float(__float_as_uint(a1.x) & 0xffff0000u);
            float r5 = a1.y - __uint_as_float(__float_as_uint(a1.y) & 0xffff0000u);
            float r6 = a1.z - __uint_as_float(__float_as_uint(a1.z) & 0xffff0000u);
            float r7 = a1.w - __uint_as_float(__float_as_uint(a1.w) & 0xffff0000u);
            alo.u[0] = PACK_HI(r0, r1);
            alo.u[1] = PACK_HI(r2, r3);
            alo.u[2] = PACK_HI(r4, r5);
            alo.u[3] = PACK_HI(r6, r7);
            acc[pt] = __builtin_amdgcn_mfma_f32_16x16x32_bf16(ahi.s, bhi.s, acc[pt], 0, 0, 0);
            acc[pt] = __builtin_amdgcn_mfma_f32_16x16x32_bf16(ahi.s, blo.s, acc[pt], 0, 0, 0);
            acc[pt] = __builtin_amdgcn_mfma_f32_16x16x32_bf16(alo.s, bhi.s, acc[pt], 0, 0, 0);
        }
        __syncthreads();   // drains prefetch vmcnt + guards buffer reuse
    }

    // ---- epilogue: bias + relu + per-cluster LDS accumulation ----
    // D-frag (verified): emb = ct*16+(lane&15), patch = pt*16+(lane>>4)*4+r
    {
        const int emb = (w << 4) + (lane & 15);
        const float bb = b1[emb];
#pragma unroll
        for (int pt = 0; pt < 2; ++pt)
#pragma unroll
            for (int r = 0; r < 4; ++r) {
                const int patch = (pt << 4) + ((lane >> 4) << 2) + r;
                float v = fmaxf(acc[pt][r] + bb, 0.f);
                atomicAdd(&csum[labs[patch]][emb], v);
            }
    }
    if (t < BP) atomicAdd(&ccnt[labs[t]], 1.0f);
    __syncthreads();

    if (use_atomic) {
        for (int i = t; i < NC * EMB; i += 256)
            atomicAdd(&psum[(size_t)bag * NC * EMB + i], (&csum[0][0])[i]);
        if (t < NC) atomicAdd(&pcnt[bag * NC + t], ccnt[t]);
    } else {
        for (int i = t; i < NC * EMB; i += 256)
            psum[(size_t)bid * NC * EMB + i] = (&csum[0][0])[i];
        if (t < NC) pcnt[bid * NC + t] = ccnt[t];
    }
}

// ---------- K2: reduce partials, means, attention, masked softmax, fc6 ------
__global__ __launch_bounds__(256) void head_kernel(
    const float* __restrict__ psum, const float* __restrict__ pcnt, int npb,
    const float* __restrict__ Wa1, const float* __restrict__ ba1,
    const float* __restrict__ Wa2, const float* __restrict__ ba2,
    const float* __restrict__ Wf1, const float* __restrict__ bf1,
    const float* __restrict__ Wf2, const float* __restrict__ bf2,
    float* __restrict__ out)
{
    __shared__ float h[NC][EMB];
    __shared__ float cnt_s[NC];
    __shared__ float mask[NC];
    __shared__ float att[NC][32];
    __shared__ float a_s[NC];
    __shared__ float A_s[NC];
    __shared__ float M_s[EMB];
    __shared__ float f_s[32];

    const int b = blockIdx.x;
    const int t = threadIdx.x;

    if (t < NC) {
        float s = 0.f;
        for (int pb = 0; pb < npb; ++pb) s += pcnt[(size_t)(b * npb + pb) * NC + t];
        cnt_s[t] = s;
        mask[t]  = s > 0.f ? 1.f : 0.f;
    }
    __syncthreads();
    for (int i = t; i < NC * EMB; i += 256) {
        float s = 0.f;
#pragma unroll 8
        for (int pb = 0; pb < npb; ++pb) s += psum[(size_t)(b * npb + pb) * NC * EMB + i];
        (&h[0][0])[i] = s / fmaxf(cnt_s[i >> 6], 1.f);
    }
    __syncthreads();

    for (int task = t; task < NC * 32; task += 256) {
        int c = task >> 5, hh = task & 31;
        float s = ba1[hh];
        for (int e = 0; e < EMB; ++e) s = fmaf(Wa1[hh * EMB + e], h[c][e], s);
        att[c][hh] = tanhf(s);
    }
    __syncthreads();

    if (t < NC) {
        float s = ba2[0];
        for (int hh = 0; hh < 32; ++hh) s = fmaf(Wa2[hh], att[t][hh], s);
        a_s[t] = s;
    }
    __syncthreads();

    if (t == 0) {
        // faithful to reference numeric trick
        float xmax = -1e30f;
        for (int c = 0; c < NC; ++c) {
            float xm = a_s[c] * mask[c] + (1.0f - 1.0f / (mask[c] + 1e-5f));
            xmax = fmaxf(xmax, xm);
        }
        float ex[NC], ssum = 0.f;
        for (int c = 0; c < NC; ++c) {
            ex[c] = expf(a_s[c] - xmax) * mask[c];
            ssum += ex[c];
        }
        for (int c = 0; c < NC; ++c) A_s[c] = ex[c] / ssum;
    }
    __syncthreads();

    if (t < EMB) {
        float s = 0.f;
        for (int c = 0; c < NC; ++c) s = fmaf(A_s[c], h[c][t], s);
        M_s[t] = s;
    }
    __syncthreads();

    if (t < 32) {
        float s = bf1[t];
        for (int e = 0; e < EMB; ++e) s = fmaf(Wf1[t * EMB + e], M_s[e], s);
        f_s[t] = fmaxf(s, 0.f);
    }
    __syncthreads();

    if (t == 0) {
        float s = bf2[0];
        for (int hh = 0; hh < 32; ++hh) s = fmaf(Wf2[hh], f_s[hh], s);
        out[b] = s;
    }
}

extern "C" void kernel_launch(void* const* d_in, const int* in_sizes, int n_in,
                              void* d_out, int out_size, void* d_ws, size_t ws_size,
                              hipStream_t stream)
{
    const float* data   = (const float*)d_in[0];
    const int*   labels = (const int*)  d_in[1];
    const float* W1     = (const float*)d_in[2];
    const float* b1     = (const float*)d_in[3];
    const float* Wa1    = (const float*)d_in[4];
    const float* ba1    = (const float*)d_in[5];
    const float* Wa2    = (const float*)d_in[6];
    const float* ba2    = (const float*)d_in[7];
    const float* Wf1    = (const float*)d_in[8];
    const float* bf1    = (const float*)d_in[9];
    const float* Wf2    = (const float*)d_in[10];
    const float* bf2    = (const float*)d_in[11];

    uint32_t* wfrag = (uint32_t*)d_ws;                       // 256KB
    float* psum = (float*)(wfrag + WFRAG_U32);

    prep_wfrag<<<64, 256, 0, stream>>>(W1, wfrag);

    const size_t need_na = (size_t)WFRAG_U32 * 4 +
                           ((size_t)NBLK * NC * EMB + (size_t)NBLK * NC) * sizeof(float);
    if (ws_size >= need_na) {
        float* pcnt = psum + (size_t)NBLK * NC * EMB;
        embed_mfma<<<NBLK, 256, 0, stream>>>(data, labels, wfrag, b1, psum, pcnt, 0);
        head_kernel<<<NB, 256, 0, stream>>>(psum, pcnt, PPB, Wa1, ba1, Wa2, ba2,
                                            Wf1, bf1, Wf2, bf2, (float*)d_out);
    } else {
        float* pcnt = psum + (size_t)NB * NC * EMB;
        hipMemsetAsync((void*)psum, 0,
                       (size_t)(NB * NC * EMB + NB * NC) * sizeof(float), stream);
        embed_mfma<<<NBLK, 256, 0, stream>>>(data, labels, wfrag, b1, psum, pcnt, 1);
        head_kernel<<<NB, 256, 0, stream>>>(psum, pcnt, 1, Wa1, ba1, Wa2, ba2,
                                            Wf1, bf1, Wf2, bf2, (float*)d_out);
    }
}